// Round 2
// baseline (660.719 us; speedup 1.0000x reference)
//
#include <hip/hip_runtime.h>
#include <stdint.h>

// R1: resubmission of R0 kernel — bench failed on container acquire (infra),
// no counters returned. No code changes warranted without evidence.

typedef __attribute__((ext_vector_type(8))) short short8;
typedef __attribute__((ext_vector_type(4))) float float4v;

#define NPIX 240
#define PIXSTRIDE 68   // shorts per pixel (64 ci + 4 pad) = 136 B: 8B-aligned rows,
                       // word-stride 34 == 2 mod 32 -> 2-way (free) conflicts

// ws layout: [0, 57344): wsA frag-ordered bf16 weights (4ct*14ks*64lane*8)
//            [57344, 58304): map (240 int, last 15 = -1)
//            [58304, 58980): out-mask (169 float)
#define MAP_OFF   57344
#define OM_OFF    58304

__device__ __forceinline__ unsigned short f2bf(float f) {
    union { float f; unsigned u; } v; v.f = f;
    unsigned r = v.u + 0x7FFFu + ((v.u >> 16) & 1u);   // RNE
    return (unsigned short)(r >> 16);
}

__global__ void hex_prep_kernel(const float* __restrict__ w,
                                unsigned short* __restrict__ wsA,
                                int* __restrict__ map,
                                float* __restrict__ om) {
    const int gid = blockIdx.x * blockDim.x + threadIdx.x;
    const int nthr = gridDim.x * blockDim.x;
    const int ti_tab[7] = {0,0,1,1,1,2,2};
    const int tj_tab[7] = {0,1,0,1,2,1,2};
    // fragment-ordered weights: item = (ct*14 + ks)*64 + lane, 8 bf16 each
    for (int item = gid; item < 4*14*64; item += nthr) {
        int lane = item & 63;
        int ks   = (item >> 6) % 14;
        int ct   = (item >> 6) / 14;
        int co = ct*16 + (lane & 15);
        int k0 = ks*32 + (lane >> 4)*8;
        unsigned short vals[8];
        #pragma unroll
        for (int j = 0; j < 8; ++j) {
            int k = k0 + j;
            int tap = k >> 6, ci = k & 63;
            vals[j] = f2bf(w[(co*64 + ci)*9 + ti_tab[tap]*3 + tj_tab[tap]]);
        }
        for (int j = 0; j < 8; ++j) wsA[item*8 + j] = vals[j];
    }
    if (gid == 0) {
        // hex padding source map: replay reference copies on indices
        int m[225];
        for (int r = 0; r < 15; ++r)
            for (int c = 0; c < 15; ++c)
                m[r*15+c] = (r>=1 && r<=13 && c>=1 && c<=13) ? (r-1)*13 + (c-1) : -1;
        #define M(r,c) m[(r)*15+(c)]
        for (int t = 0; t < 7; ++t) M(0,1+t)    = M(12,7+t);
        for (int r = 0; r < 3; ++r) M(r,8+r)    = M(6+r,2+r);
        for (int r = 0; r < 4; ++r) M(3+r,10+r) = M(9+r,4+r);
        for (int r = 0; r < 3; ++r) M(7+r,13)   = M(1+r,1);
        for (int r = 0; r < 3; ++r) M(10+r,14)  = M(4+r,2);
        for (int r = 0; r < 8; ++r) M(13,7+r)   = M(1,1+r);
        for (int r = 0; r < 4; ++r) M(9+r,3+r)  = M(3+r,9+r);
        for (int r = 0; r < 3; ++r) M(6+r,1+r)  = M(r,7+r);
        for (int r = 0; r < 2; ++r) M(4+r,1)    = M(10+r,13);
        for (int r = 0; r < 4; ++r) M(r,0)      = M(6+r,12);
        #undef M
        for (int i = 0; i < 225; ++i) map[i] = m[i];
        for (int i = 225; i < 240; ++i) map[i] = -1;
        // output mask
        float o[169];
        for (int i = 0; i < 169; ++i) o[i] = 1.f;
        for (int i = 0; i < 5; ++i) for (int j = 8+i; j < 13; ++j) o[i*13+j] = 0.f;
        for (int i = 0; i < 4; ++i) o[(2+i)*13 + 9+i] = 0.f;
        for (int i = 6; i < 9; ++i) o[i*13 + 12] = 0.f;
        for (int i = 0; i < 6; ++i) for (int j = 0; j <= i; ++j) o[(6+i)*13 + j] = 0.f;
        for (int i = 0; i < 3; ++i) o[(5+i)*13 + i] = 0.f;
        o[3*13 + 0] = 0.f; o[4*13 + 0] = 0.f;
        for (int i = 0; i < 169; ++i) om[i] = o[i];
    }
}

// Persistent, double-buffered version.
// Grid = 512 blocks (2/CU by LDS: 2 x 32640 B), each block owns a contiguous
// chunk of images. Per block, ONCE: A-frags (112 VGPR), map, bias, epilogue
// geometry. Per image: async-STAGE split pipeline -- issue next-image global
// loads before each MFMA half, convert+LDS-write after; one barrier per image;
// epilogue stores issued AFTER the barrier so they overlap the next image's
// MFMA and drain a full image later.
__global__ __launch_bounds__(256, 2) void hexconv_kernel(
        const float* __restrict__ x, const float* __restrict__ bias,
        const unsigned short* __restrict__ wsA, const int* __restrict__ map,
        const float* __restrict__ om, float* __restrict__ out,
        int B, int ipb) {
    __shared__ unsigned short Xs[2][NPIX * PIXSTRIDE];
    const int tid = threadIdx.x;
    const int lane = tid & 63, wv = tid >> 6;
    const int lr = lane & 15, lq = lane >> 4;
    const int ctp = wv & 1;
    const int nth = wv >> 1;

    const int b0   = blockIdx.x * ipb;
    const int bend = (b0 + ipb < B) ? (b0 + ipb) : B;
    if (b0 >= bend) return;

    // ---- per-block constants (loaded ONCE, not per image) ----
    short8 afr[2][14];
    #pragma unroll
    for (int c = 0; c < 2; ++c) {
        const int ct = ctp*2 + c;
        #pragma unroll
        for (int ks = 0; ks < 14; ++ks)
            afr[c][ks] = *(const short8*)(wsA + (size_t)((ct*14 + ks)*64 + lane)*8);
    }
    int sp[4];
    #pragma unroll
    for (int pi = 0; pi < 4; ++pi) {
        int pix = lane + 64*pi;
        sp[pi] = (pix < NPIX) ? map[pix] : -1;
    }
    float biasv[2][4];
    #pragma unroll
    for (int c = 0; c < 2; ++c)
        #pragma unroll
        for (int r = 0; r < 4; ++r)
            biasv[c][r] = bias[(ctp*2 + c)*16 + lq*4 + r];
    // epilogue geometry: co row = ct*16+lq*4+r, col p15 = nt*16+lr
    int ep_off[7]; float ep_om[7]; unsigned okmask = 0;
    #pragma unroll
    for (int j = 0; j < 7; ++j) {
        int nt = nth*7 + j;
        int p15 = nt*16 + lr;
        int y = p15 / 15, xc = p15 % 15;
        bool ok = (nt < 13) && (xc < 13) && (y < 13);
        ep_off[j] = ok ? (y*13 + xc) : 0;
        ep_om[j]  = ok ? om[y*13 + xc] : 0.f;
        if (ok) okmask |= (1u << j);
    }

    // ---- staging helpers: lane <-> pixel, wave <-> ci-block ----
    auto issue2 = [&](const float* __restrict__ xb, int pp, float (&lv)[2][16]) {
        #pragma unroll
        for (int h = 0; h < 2; ++h) {
            int pi = 2*pp + h;
            int pix = lane + 64*pi;
            if (pix < NPIX) {
                int s = sp[pi];
                #pragma unroll
                for (int cj = 0; cj < 16; ++cj)
                    lv[h][cj] = (s >= 0) ? xb[(wv*16 + cj)*169 + s] : 0.f;
            }
        }
    };
    auto cwrite2 = [&](int sel, int pp, const float (&lv)[2][16]) {
        #pragma unroll
        for (int h = 0; h < 2; ++h) {
            int pi = 2*pp + h;
            int pix = lane + 64*pi;
            if (pix < NPIX) {
                #pragma unroll
                for (int q = 0; q < 4; ++q) {
                    uint64_t pk = (uint64_t)f2bf(lv[h][4*q])
                                | ((uint64_t)f2bf(lv[h][4*q+1]) << 16)
                                | ((uint64_t)f2bf(lv[h][4*q+2]) << 32)
                                | ((uint64_t)f2bf(lv[h][4*q+3]) << 48);
                    *(uint64_t*)&Xs[sel][pix*PIXSTRIDE + wv*16 + q*4] = pk;
                }
            }
        }
    };

    const int offs[7] = {0,1,15,16,17,31,32};   // ti*15+tj for the 7 hex taps

#define MFMA_HALF(SEL, KBASE) do {                                            \
    _Pragma("unroll")                                                         \
    for (int kk = 0; kk < 7; ++kk) {                                          \
        const int ks = (KBASE) + kk;                                          \
        const int tap = ks >> 1;               /* k-step never straddles */   \
        const int cib = (ks & 1)*32 + lq*8;                                   \
        _Pragma("unroll")                                                     \
        for (int j = 0; j < 7; ++j) {                                         \
            int nt = nth*7 + j;                                               \
            if (nt < 13) {                                                    \
                int pixb = nt*16 + lr + offs[tap];                            \
                const unsigned short* p = &Xs[SEL][pixb*PIXSTRIDE + cib];     \
                union { short8 v; uint64_t q[2]; } u;                         \
                u.q[0] = *(const uint64_t*)p;                                 \
                u.q[1] = *(const uint64_t*)(p + 4);                           \
                _Pragma("unroll")                                             \
                for (int c = 0; c < 2; ++c)                                   \
                    acc[c][j] = __builtin_amdgcn_mfma_f32_16x16x32_bf16(      \
                        afr[c][ks], u.v, acc[c][j], 0, 0, 0);                 \
            }                                                                 \
        }                                                                     \
    }                                                                         \
} while (0)

    // ---- prologue: stage first image into buffer 0 ----
    {
        const float* xb = x + (size_t)b0 * 64 * 169;
        float lv[2][16];
        issue2(xb, 0, lv);
        cwrite2(0, 0, lv);
        issue2(xb, 1, lv);
        cwrite2(0, 1, lv);
    }
    __syncthreads();

    int cur = 0;
    for (int b = b0; b < bend; ++b) {
        const bool havenext = (b + 1 < bend);
        const float* xbn = x + (size_t)(b + 1) * 64 * 169;

        float4v acc[2][7];
        #pragma unroll
        for (int c = 0; c < 2; ++c)
            #pragma unroll
            for (int j = 0; j < 7; ++j)
                acc[c][j] = float4v{0.f, 0.f, 0.f, 0.f};

        float lv[2][16];
        if (havenext) issue2(xbn, 0, lv);          // loads fly under MFMA half 1

        MFMA_HALF(cur, 0);

        if (havenext) {
            cwrite2(cur ^ 1, 0, lv);               // waitcnt here, latency covered
            issue2(xbn, 1, lv);                    // loads fly under MFMA half 2
        }

        MFMA_HALF(cur, 7);

        if (havenext) cwrite2(cur ^ 1, 1, lv);

        __syncthreads();                            // one barrier per image

        // ---- epilogue AFTER barrier: stores overlap next image's MFMA ----
        #pragma unroll
        for (int j = 0; j < 7; ++j) {
            if (!((okmask >> j) & 1u)) continue;
            size_t obase = (size_t)b * (64*169) + ep_off[j];
            float omv = ep_om[j];
            #pragma unroll
            for (int c = 0; c < 2; ++c) {
                #pragma unroll
                for (int r = 0; r < 4; ++r) {
                    int co = (ctp*2 + c)*16 + lq*4 + r;
                    out[obase + (size_t)co*169] = (acc[c][j][r] + biasv[c][r]) * omv;
                }
            }
        }

        cur ^= 1;
    }
#undef MFMA_HALF
}

extern "C" void kernel_launch(void* const* d_in, const int* in_sizes, int n_in,
                              void* d_out, int out_size, void* d_ws, size_t ws_size,
                              hipStream_t stream) {
    const float* x    = (const float*)d_in[0];
    const float* w    = (const float*)d_in[1];
    const float* bias = (const float*)d_in[2];
    float* out = (float*)d_out;

    unsigned short* wsA = (unsigned short*)d_ws;
    int*   map = (int*)((char*)d_ws + MAP_OFF);
    float* om  = (float*)((char*)d_ws + OM_OFF);

    hex_prep_kernel<<<16, 256, 0, stream>>>(w, wsA, map, om);

    int B = in_sizes[0] / (64 * 169);   // 4096 images
    int nblk = 512;                     // 2 blocks/CU (LDS-capped), persistent
    if (nblk > B) nblk = B;
    int ipb = (B + nblk - 1) / nblk;
    hexconv_kernel<<<nblk, 256, 0, stream>>>(x, bias, wsA, map, om, out, B, ipb);
}